// Round 1
// baseline (652.284 us; speedup 1.0000x reference)
//
#include <hip/hip_runtime.h>

// Quadratic positional encoding, fused:
//   out = (E0@Wr + br) * (E@Wg + bg) + (E*E)@Wb + bb,  E = 36-dim trig encoding
// N=1e6 points, OUT=256. Output 1.02 GB f32 -> store-BW bound (~163us floor).
// bf16 MFMA (32x32x16) for the three K=36 (padded 48) GEMMs; x,y and x^2,y^2
// terms kept in f32 via epilogue sideband to stay inside the absmax threshold.

typedef short bf16x8 __attribute__((ext_vector_type(8)));
typedef short bf16x4 __attribute__((ext_vector_type(4)));
typedef float f32x16 __attribute__((ext_vector_type(16)));

__device__ __forceinline__ unsigned short f2bf(float x) {
  unsigned int u = __float_as_uint(x);
  return (unsigned short)((u + 0x7FFFu + ((u >> 16) & 1u)) >> 16);  // RNE
}

// a in radians; v_sin/v_cos take revolutions, reduce with fract first
__device__ __forceinline__ void fsincos(float a, float* s, float* c) {
  float r = a * 0.15915494309189535f;
  r = r - floorf(r);
  *s = __builtin_amdgcn_sinf(r);
  *c = __builtin_amdgcn_cosf(r);
}

// Reordered K layout (k'):
//   k' 0..31  : freq f = k'>>2, comp {sin px, cos px, sin py, cos py} (orig k = k'+4)
//   k' 32..35 : header {x, y, sin base, cos base} (orig k = k'-32); rows 32,33 zeroed in B
//   k' 36..47 : zero pad
__global__ __launch_bounds__(256, 2) void qpe_kernel(
    const float* __restrict__ X, const float* __restrict__ Y,
    const float* __restrict__ V, const float* __restrict__ V0,
    const float* __restrict__ Wr, const float* __restrict__ Wg,
    const float* __restrict__ Wb, const float* __restrict__ Br,
    const float* __restrict__ Bg, const float* __restrict__ Bb,
    float* __restrict__ Out, int nt)
{
  __shared__ __align__(16) unsigned short enc[3][64][64];  // 24.5 KB, rows 128B, XOR-swizzled
  __shared__ float4 xyl[64];                               // f32 sideband {x,y,x2,y2}

  const int tid  = threadIdx.x;
  const int lane = tid & 63;
  const int wid  = tid >> 6;   // wave 0..3 -> col block wid*64
  const int hi   = lane >> 5;  // 0/1
  const int ln   = lane & 31;

  // ---- zero entire enc LDS once: keeps k'=36..47 pad zero forever ----
  {
    bf16x8 z = {0,0,0,0,0,0,0,0};
    bf16x8* pz = (bf16x8*)(&enc[0][0][0]);
#pragma unroll
    for (int i = 0; i < 6; ++i) pz[tid + 256 * i] = z;
  }

  // ---- resident B fragments (3 mats x 3 K-steps x 2 col-tiles) + sideband ----
  bf16x8 Bf[2][3][3];
  float  wc[2][6];   // Wr[0],Wr[1],Wg[0],Wg[1],Wb[0],Wb[1] at this col
  float  bs[2][3];   // br, bg, bb at this col
  {
    const float* const Wm[3] = {Wr, Wg, Wb};
#pragma unroll
    for (int ct = 0; ct < 2; ++ct) {
      int col = wid * 64 + ct * 32 + ln;
#pragma unroll
      for (int m = 0; m < 3; ++m) {
#pragma unroll
        for (int s = 0; s < 3; ++s) {
          bf16x8 f;
#pragma unroll
          for (int j = 0; j < 8; ++j) {
            int kp = s * 16 + hi * 8 + j;
            float val = 0.0f;
            if (kp < 32) val = Wm[m][(kp + 4) * 256 + col];
            else if (kp == 34 || kp == 35) val = Wm[m][(kp - 32) * 256 + col];
            f[j] = (short)f2bf(val);
          }
          Bf[ct][m][s] = f;
        }
      }
      wc[ct][0] = Wr[col];       wc[ct][1] = Wr[256 + col];
      wc[ct][2] = Wg[col];       wc[ct][3] = Wg[256 + col];
      wc[ct][4] = Wb[col];       wc[ct][5] = Wb[256 + col];
      bs[ct][0] = Br[col];       bs[ct][1] = Bg[col];       bs[ct][2] = Bb[col];
    }
  }
  __syncthreads();

  const float TPF = 62.831853071795864f;  // 2*pi*10
  const int   pl = tid >> 2;              // point-local 0..63
  const int   qq = tid & 3;               // freq pair: f = 2q, 2q+1
  const float scA = __int_as_float((124 + 2 * qq) << 23);  // 2^(2q-3)
  const float scB = scA + scA;

  for (int t = blockIdx.x; t < nt; t += gridDim.x) {
    // ======== E phase: 64 points x 4 threads each ========
    {
      size_t pt = (size_t)t * 64 + pl;
      float xx = X[pt], yy = Y[pt];
      float wn  = TPF / V[pt];
      float wn0 = TPF / V0[pt];
      float xw0 = xx * wn0, yw0 = yy * wn0, xw = xx * wn, yw = yy * wn;
      bf16x8 e0, e1, e2;
      float s, c;
      fsincos(xw0 * scA, &s, &c); e0[0] = (short)f2bf(s); e0[1] = (short)f2bf(c);
      fsincos(yw0 * scA, &s, &c); e0[2] = (short)f2bf(s); e0[3] = (short)f2bf(c);
      fsincos(xw0 * scB, &s, &c); e0[4] = (short)f2bf(s); e0[5] = (short)f2bf(c);
      fsincos(yw0 * scB, &s, &c); e0[6] = (short)f2bf(s); e0[7] = (short)f2bf(c);
      fsincos(xw * scA, &s, &c);  e1[0] = (short)f2bf(s); e1[1] = (short)f2bf(c);
                                  e2[0] = (short)f2bf(s * s); e2[1] = (short)f2bf(c * c);
      fsincos(yw * scA, &s, &c);  e1[2] = (short)f2bf(s); e1[3] = (short)f2bf(c);
                                  e2[2] = (short)f2bf(s * s); e2[3] = (short)f2bf(c * c);
      fsincos(xw * scB, &s, &c);  e1[4] = (short)f2bf(s); e1[5] = (short)f2bf(c);
                                  e2[4] = (short)f2bf(s * s); e2[5] = (short)f2bf(c * c);
      fsincos(yw * scB, &s, &c);  e1[6] = (short)f2bf(s); e1[7] = (short)f2bf(c);
                                  e2[6] = (short)f2bf(s * s); e2[7] = (short)f2bf(c * c);
      int swz = (pl & 7) << 4;
      *(bf16x8*)((char*)&enc[0][pl][0] + ((16 * qq) ^ swz)) = e0;
      *(bf16x8*)((char*)&enc[1][pl][0] + ((16 * qq) ^ swz)) = e1;
      *(bf16x8*)((char*)&enc[2][pl][0] + ((16 * qq) ^ swz)) = e2;
      if (qq == 0) {
        float s0, c0, s1, c1;
        fsincos(xw0 * 0.0625f, &s0, &c0);
        fsincos(xw  * 0.0625f, &s1, &c1);
        bf16x4 h0, h1, h2;
        h0[0] = (short)f2bf(xx); h0[1] = (short)f2bf(yy);
        h0[2] = (short)f2bf(s0); h0[3] = (short)f2bf(c0);
        h1[0] = (short)f2bf(xx); h1[1] = (short)f2bf(yy);
        h1[2] = (short)f2bf(s1); h1[3] = (short)f2bf(c1);
        h2[0] = (short)f2bf(xx * xx); h2[1] = (short)f2bf(yy * yy);
        h2[2] = (short)f2bf(s1 * s1); h2[3] = (short)f2bf(c1 * c1);
        *(bf16x4*)((char*)&enc[0][pl][0] + (64 ^ swz)) = h0;
        *(bf16x4*)((char*)&enc[1][pl][0] + (64 ^ swz)) = h1;
        *(bf16x4*)((char*)&enc[2][pl][0] + (64 ^ swz)) = h2;
        xyl[pl] = make_float4(xx, yy, xx * xx, yy * yy);
      }
    }
    __syncthreads();

    // ======== M phase: 2 row-tiles x 2 col-tiles per wave ========
#pragma unroll
    for (int rt = 0; rt < 2; ++rt) {
      bf16x8 Af[3][3];
      int p = rt * 32 + ln;
      int swz2 = (p & 7) << 4;
#pragma unroll
      for (int m = 0; m < 3; ++m)
#pragma unroll
        for (int s = 0; s < 3; ++s)
          Af[m][s] = *(const bf16x8*)((const char*)&enc[m][p][0] +
                                      ((s * 32 + hi * 16) ^ swz2));
#pragma unroll
      for (int ct = 0; ct < 2; ++ct) {
        f32x16 ar, ag, aq;
#pragma unroll
        for (int i = 0; i < 16; ++i) { ar[i] = 0.f; ag[i] = 0.f; aq[i] = 0.f; }
#pragma unroll
        for (int s = 0; s < 3; ++s) {
          ar = __builtin_amdgcn_mfma_f32_32x32x16_bf16(Af[0][s], Bf[ct][0][s], ar, 0, 0, 0);
          ag = __builtin_amdgcn_mfma_f32_32x32x16_bf16(Af[1][s], Bf[ct][1][s], ag, 0, 0, 0);
          aq = __builtin_amdgcn_mfma_f32_32x32x16_bf16(Af[2][s], Bf[ct][2][s], aq, 0, 0, 0);
        }
        int col = wid * 64 + ct * 32 + ln;
        float* outp = Out + (size_t)(t * 64 + rt * 32) * 256 + col;
#pragma unroll
        for (int i = 0; i < 16; ++i) {
          int rl = (i & 3) + 8 * (i >> 2) + 4 * hi;   // row within 32-tile
          float4 xy = xyl[rt * 32 + rl];
          float rr = ar[i] + xy.x * wc[ct][0] + xy.y * wc[ct][1] + bs[ct][0];
          float gg = ag[i] + xy.x * wc[ct][2] + xy.y * wc[ct][3] + bs[ct][1];
          float qv = aq[i] + xy.z * wc[ct][4] + xy.w * wc[ct][5] + bs[ct][2];
          outp[(size_t)rl * 256] = rr * gg + qv;
        }
      }
    }
    __syncthreads();
  }
}

extern "C" void kernel_launch(void* const* d_in, const int* in_sizes, int n_in,
                              void* d_out, int out_size, void* d_ws, size_t ws_size,
                              hipStream_t stream) {
  const float* X  = (const float*)d_in[0];
  const float* Y  = (const float*)d_in[1];
  const float* V  = (const float*)d_in[2];
  const float* V0 = (const float*)d_in[3];
  const float* Wr = (const float*)d_in[4];
  const float* Wg = (const float*)d_in[5];
  const float* Wb = (const float*)d_in[6];
  const float* Br = (const float*)d_in[7];
  const float* Bg = (const float*)d_in[8];
  const float* Bb = (const float*)d_in[9];
  float* Out = (float*)d_out;
  int n  = in_sizes[0];
  int nt = n >> 6;  // N=1e6 is divisible by 64
  qpe_kernel<<<dim3(512), dim3(256), 0, stream>>>(X, Y, V, V0, Wr, Wg, Wb,
                                                  Br, Bg, Bb, Out, nt);
}

// Round 2
// 617.840 us; speedup vs baseline: 1.0557x; 1.0557x over previous
//
#include <hip/hip_runtime.h>

// Quadratic positional encoding, fused:
//   out = (E0@Wr + br) * (E@Wg + bg) + (E*E)@Wb + bb,  E = 36-dim trig encoding
// N=1e6 points, OUT=256. Output 1.02 GB f32 -> store-BW bound.
// R2: non-temporal output stores (kill 1.3 GB write-allocate FETCH), grid 1024.

typedef short bf16x8 __attribute__((ext_vector_type(8)));
typedef short bf16x4 __attribute__((ext_vector_type(4)));
typedef float f32x16 __attribute__((ext_vector_type(16)));

__device__ __forceinline__ unsigned short f2bf(float x) {
  unsigned int u = __float_as_uint(x);
  return (unsigned short)((u + 0x7FFFu + ((u >> 16) & 1u)) >> 16);  // RNE
}

// a in radians; v_sin/v_cos take revolutions, reduce with fract first
__device__ __forceinline__ void fsincos(float a, float* s, float* c) {
  float r = a * 0.15915494309189535f;
  r = r - floorf(r);
  *s = __builtin_amdgcn_sinf(r);
  *c = __builtin_amdgcn_cosf(r);
}

// Reordered K layout (k'):
//   k' 0..31  : freq f = k'>>2, comp {sin px, cos px, sin py, cos py} (orig k = k'+4)
//   k' 32..35 : header {x, y, sin base, cos base} (orig k = k'-32); rows 32,33 zeroed in B
//   k' 36..47 : zero pad
__global__ __launch_bounds__(256, 2) void qpe_kernel(
    const float* __restrict__ X, const float* __restrict__ Y,
    const float* __restrict__ V, const float* __restrict__ V0,
    const float* __restrict__ Wr, const float* __restrict__ Wg,
    const float* __restrict__ Wb, const float* __restrict__ Br,
    const float* __restrict__ Bg, const float* __restrict__ Bb,
    float* __restrict__ Out, int nt)
{
  __shared__ __align__(16) unsigned short enc[3][64][64];  // 24.5 KB, rows 128B, XOR-swizzled
  __shared__ float4 xyl[64];                               // f32 sideband {x,y,x2,y2}

  const int tid  = threadIdx.x;
  const int lane = tid & 63;
  const int wid  = tid >> 6;   // wave 0..3 -> col block wid*64
  const int hi   = lane >> 5;  // 0/1
  const int ln   = lane & 31;

  // ---- zero entire enc LDS once: keeps k'=36..47 pad zero forever ----
  {
    bf16x8 z = {0,0,0,0,0,0,0,0};
    bf16x8* pz = (bf16x8*)(&enc[0][0][0]);
#pragma unroll
    for (int i = 0; i < 6; ++i) pz[tid + 256 * i] = z;
  }

  // ---- resident B fragments (3 mats x 3 K-steps x 2 col-tiles) + sideband ----
  bf16x8 Bf[2][3][3];
  float  wc[2][6];   // Wr[0],Wr[1],Wg[0],Wg[1],Wb[0],Wb[1] at this col
  float  bs[2][3];   // br, bg, bb at this col
  {
    const float* const Wm[3] = {Wr, Wg, Wb};
#pragma unroll
    for (int ct = 0; ct < 2; ++ct) {
      int col = wid * 64 + ct * 32 + ln;
#pragma unroll
      for (int m = 0; m < 3; ++m) {
#pragma unroll
        for (int s = 0; s < 3; ++s) {
          bf16x8 f;
#pragma unroll
          for (int j = 0; j < 8; ++j) {
            int kp = s * 16 + hi * 8 + j;
            float val = 0.0f;
            if (kp < 32) val = Wm[m][(kp + 4) * 256 + col];
            else if (kp == 34 || kp == 35) val = Wm[m][(kp - 32) * 256 + col];
            f[j] = (short)f2bf(val);
          }
          Bf[ct][m][s] = f;
        }
      }
      wc[ct][0] = Wr[col];       wc[ct][1] = Wr[256 + col];
      wc[ct][2] = Wg[col];       wc[ct][3] = Wg[256 + col];
      wc[ct][4] = Wb[col];       wc[ct][5] = Wb[256 + col];
      bs[ct][0] = Br[col];       bs[ct][1] = Bg[col];       bs[ct][2] = Bb[col];
    }
  }
  __syncthreads();

  const float TPF = 62.831853071795864f;  // 2*pi*10
  const int   pl = tid >> 2;              // point-local 0..63
  const int   qq = tid & 3;               // freq pair: f = 2q, 2q+1
  const float scA = __int_as_float((124 + 2 * qq) << 23);  // 2^(2q-3)
  const float scB = scA + scA;

  for (int t = blockIdx.x; t < nt; t += gridDim.x) {
    // ======== E phase: 64 points x 4 threads each ========
    {
      size_t pt = (size_t)t * 64 + pl;
      float xx = X[pt], yy = Y[pt];
      float wn  = TPF / V[pt];
      float wn0 = TPF / V0[pt];
      float xw0 = xx * wn0, yw0 = yy * wn0, xw = xx * wn, yw = yy * wn;
      bf16x8 e0, e1, e2;
      float s, c;
      fsincos(xw0 * scA, &s, &c); e0[0] = (short)f2bf(s); e0[1] = (short)f2bf(c);
      fsincos(yw0 * scA, &s, &c); e0[2] = (short)f2bf(s); e0[3] = (short)f2bf(c);
      fsincos(xw0 * scB, &s, &c); e0[4] = (short)f2bf(s); e0[5] = (short)f2bf(c);
      fsincos(yw0 * scB, &s, &c); e0[6] = (short)f2bf(s); e0[7] = (short)f2bf(c);
      fsincos(xw * scA, &s, &c);  e1[0] = (short)f2bf(s); e1[1] = (short)f2bf(c);
                                  e2[0] = (short)f2bf(s * s); e2[1] = (short)f2bf(c * c);
      fsincos(yw * scA, &s, &c);  e1[2] = (short)f2bf(s); e1[3] = (short)f2bf(c);
                                  e2[2] = (short)f2bf(s * s); e2[3] = (short)f2bf(c * c);
      fsincos(xw * scB, &s, &c);  e1[4] = (short)f2bf(s); e1[5] = (short)f2bf(c);
                                  e2[4] = (short)f2bf(s * s); e2[5] = (short)f2bf(c * c);
      fsincos(yw * scB, &s, &c);  e1[6] = (short)f2bf(s); e1[7] = (short)f2bf(c);
                                  e2[6] = (short)f2bf(s * s); e2[7] = (short)f2bf(c * c);
      int swz = (pl & 7) << 4;
      *(bf16x8*)((char*)&enc[0][pl][0] + ((16 * qq) ^ swz)) = e0;
      *(bf16x8*)((char*)&enc[1][pl][0] + ((16 * qq) ^ swz)) = e1;
      *(bf16x8*)((char*)&enc[2][pl][0] + ((16 * qq) ^ swz)) = e2;
      if (qq == 0) {
        float s0, c0, s1, c1;
        fsincos(xw0 * 0.0625f, &s0, &c0);
        fsincos(xw  * 0.0625f, &s1, &c1);
        bf16x4 h0, h1, h2;
        h0[0] = (short)f2bf(xx); h0[1] = (short)f2bf(yy);
        h0[2] = (short)f2bf(s0); h0[3] = (short)f2bf(c0);
        h1[0] = (short)f2bf(xx); h1[1] = (short)f2bf(yy);
        h1[2] = (short)f2bf(s1); h1[3] = (short)f2bf(c1);
        h2[0] = (short)f2bf(xx * xx); h2[1] = (short)f2bf(yy * yy);
        h2[2] = (short)f2bf(s1 * s1); h2[3] = (short)f2bf(c1 * c1);
        *(bf16x4*)((char*)&enc[0][pl][0] + (64 ^ swz)) = h0;
        *(bf16x4*)((char*)&enc[1][pl][0] + (64 ^ swz)) = h1;
        *(bf16x4*)((char*)&enc[2][pl][0] + (64 ^ swz)) = h2;
        xyl[pl] = make_float4(xx, yy, xx * xx, yy * yy);
      }
    }
    __syncthreads();

    // ======== M phase: 2 row-tiles x 2 col-tiles per wave ========
#pragma unroll
    for (int rt = 0; rt < 2; ++rt) {
      bf16x8 Af[3][3];
      int p = rt * 32 + ln;
      int swz2 = (p & 7) << 4;
#pragma unroll
      for (int m = 0; m < 3; ++m)
#pragma unroll
        for (int s = 0; s < 3; ++s)
          Af[m][s] = *(const bf16x8*)((const char*)&enc[m][p][0] +
                                      ((s * 32 + hi * 16) ^ swz2));
#pragma unroll
      for (int ct = 0; ct < 2; ++ct) {
        f32x16 ar, ag, aq;
#pragma unroll
        for (int i = 0; i < 16; ++i) { ar[i] = 0.f; ag[i] = 0.f; aq[i] = 0.f; }
#pragma unroll
        for (int s = 0; s < 3; ++s) {
          ar = __builtin_amdgcn_mfma_f32_32x32x16_bf16(Af[0][s], Bf[ct][0][s], ar, 0, 0, 0);
          ag = __builtin_amdgcn_mfma_f32_32x32x16_bf16(Af[1][s], Bf[ct][1][s], ag, 0, 0, 0);
          aq = __builtin_amdgcn_mfma_f32_32x32x16_bf16(Af[2][s], Bf[ct][2][s], aq, 0, 0, 0);
        }
        int col = wid * 64 + ct * 32 + ln;
        float* outp = Out + (size_t)(t * 64 + rt * 32) * 256 + col;
#pragma unroll
        for (int i = 0; i < 16; ++i) {
          int rl = (i & 3) + 8 * (i >> 2) + 4 * hi;   // row within 32-tile
          float4 xy = xyl[rt * 32 + rl];
          float rr = ar[i] + xy.x * wc[ct][0] + xy.y * wc[ct][1] + bs[ct][0];
          float gg = ag[i] + xy.x * wc[ct][2] + xy.y * wc[ct][3] + bs[ct][1];
          float qv = aq[i] + xy.z * wc[ct][4] + xy.w * wc[ct][5] + bs[ct][2];
          // non-temporal: no L2 allocate -> no write-allocate RFO fetch
          __builtin_nontemporal_store(rr * gg + qv, outp + (size_t)rl * 256);
        }
      }
    }
    __syncthreads();
  }
}

extern "C" void kernel_launch(void* const* d_in, const int* in_sizes, int n_in,
                              void* d_out, int out_size, void* d_ws, size_t ws_size,
                              hipStream_t stream) {
  const float* X  = (const float*)d_in[0];
  const float* Y  = (const float*)d_in[1];
  const float* V  = (const float*)d_in[2];
  const float* V0 = (const float*)d_in[3];
  const float* Wr = (const float*)d_in[4];
  const float* Wg = (const float*)d_in[5];
  const float* Wb = (const float*)d_in[6];
  const float* Br = (const float*)d_in[7];
  const float* Bg = (const float*)d_in[8];
  const float* Bb = (const float*)d_in[9];
  float* Out = (float*)d_out;
  int n  = in_sizes[0];
  int nt = n >> 6;  // N=1e6 is divisible by 64
  qpe_kernel<<<dim3(1024), dim3(256), 0, stream>>>(X, Y, V, V0, Wr, Wg, Wb,
                                                   Br, Bg, Bb, Out, nt);
}

// Round 4
// 356.539 us; speedup vs baseline: 1.8295x; 1.7329x over previous
//
#include <hip/hip_runtime.h>

// Quadratic positional encoding, fused:
//   out = (E0@Wr + br) * (E@Wg + bg) + (E*E)@Wb + bb,  E = 36-dim trig encoding
// N=1e6 points, OUT=256. Output 1.02 GB f32 -> store-BW bound.
// R4 = R3 with compile fix: ext_vector float4 for nontemporal_store.
// Stage output tile in LDS, store full 1KB rows per wave-instruction
// (global_store_dwordx4, 64 lanes x 16B contiguous) to kill the ~1.2 GB
// write-allocate FETCH seen in R1/R2.

typedef short bf16x8 __attribute__((ext_vector_type(8)));
typedef short bf16x4 __attribute__((ext_vector_type(4)));
typedef float f32x16 __attribute__((ext_vector_type(16)));
typedef float f32x4  __attribute__((ext_vector_type(4)));

__device__ __forceinline__ unsigned short f2bf(float x) {
  unsigned int u = __float_as_uint(x);
  return (unsigned short)((u + 0x7FFFu + ((u >> 16) & 1u)) >> 16);  // RNE
}

// a in radians; v_sin/v_cos take revolutions, reduce with fract first
__device__ __forceinline__ void fsincos(float a, float* s, float* c) {
  float r = a * 0.15915494309189535f;
  r = r - floorf(r);
  *s = __builtin_amdgcn_sinf(r);
  *c = __builtin_amdgcn_cosf(r);
}

// Reordered K layout (k'):
//   k' 0..31  : freq f = k'>>2, comp {sin px, cos px, sin py, cos py} (orig k = k'+4)
//   k' 32..35 : header {x, y, sin base, cos base} (orig k = k'-32); rows 32,33 zeroed in B
//   k' 36..47 : zero pad
__global__ __launch_bounds__(256, 2) void qpe_kernel(
    const float* __restrict__ X, const float* __restrict__ Y,
    const float* __restrict__ V, const float* __restrict__ V0,
    const float* __restrict__ Wr, const float* __restrict__ Wg,
    const float* __restrict__ Wb, const float* __restrict__ Br,
    const float* __restrict__ Bg, const float* __restrict__ Bb,
    float* __restrict__ Out, int nt)
{
  __shared__ __align__(16) unsigned short enc[3][64][64];  // 24.5 KB, rows 128B, XOR-swizzled
  __shared__ float4 xyl[64];                               // f32 sideband {x,y,x2,y2}
  __shared__ __align__(16) float outt[32][256];            // 32 KB output staging (one rt tile)

  const int tid  = threadIdx.x;
  const int lane = tid & 63;
  const int wid  = tid >> 6;   // wave 0..3 -> col block wid*64
  const int hi   = lane >> 5;  // 0/1
  const int ln   = lane & 31;

  // ---- zero entire enc LDS once: keeps k'=36..47 pad zero forever ----
  {
    bf16x8 z = {0,0,0,0,0,0,0,0};
    bf16x8* pz = (bf16x8*)(&enc[0][0][0]);
#pragma unroll
    for (int i = 0; i < 6; ++i) pz[tid + 256 * i] = z;
  }

  // ---- resident B fragments (3 mats x 3 K-steps x 2 col-tiles) + sideband ----
  bf16x8 Bf[2][3][3];
  float  wc[2][6];   // Wr[0],Wr[1],Wg[0],Wg[1],Wb[0],Wb[1] at this col
  float  bs[2][3];   // br, bg, bb at this col
  {
    const float* const Wm[3] = {Wr, Wg, Wb};
#pragma unroll
    for (int ct = 0; ct < 2; ++ct) {
      int col = wid * 64 + ct * 32 + ln;
#pragma unroll
      for (int m = 0; m < 3; ++m) {
#pragma unroll
        for (int s = 0; s < 3; ++s) {
          bf16x8 f;
#pragma unroll
          for (int j = 0; j < 8; ++j) {
            int kp = s * 16 + hi * 8 + j;
            float val = 0.0f;
            if (kp < 32) val = Wm[m][(kp + 4) * 256 + col];
            else if (kp == 34 || kp == 35) val = Wm[m][(kp - 32) * 256 + col];
            f[j] = (short)f2bf(val);
          }
          Bf[ct][m][s] = f;
        }
      }
      wc[ct][0] = Wr[col];       wc[ct][1] = Wr[256 + col];
      wc[ct][2] = Wg[col];       wc[ct][3] = Wg[256 + col];
      wc[ct][4] = Wb[col];       wc[ct][5] = Wb[256 + col];
      bs[ct][0] = Br[col];       bs[ct][1] = Bg[col];       bs[ct][2] = Bb[col];
    }
  }
  __syncthreads();

  const float TPF = 62.831853071795864f;  // 2*pi*10
  const int   pl = tid >> 2;              // point-local 0..63
  const int   qq = tid & 3;               // freq pair: f = 2q, 2q+1
  const float scA = __int_as_float((124 + 2 * qq) << 23);  // 2^(2q-3)
  const float scB = scA + scA;

  for (int t = blockIdx.x; t < nt; t += gridDim.x) {
    // ======== E phase: 64 points x 4 threads each ========
    {
      size_t pt = (size_t)t * 64 + pl;
      float xx = X[pt], yy = Y[pt];
      float wn  = TPF / V[pt];
      float wn0 = TPF / V0[pt];
      float xw0 = xx * wn0, yw0 = yy * wn0, xw = xx * wn, yw = yy * wn;
      bf16x8 e0, e1, e2;
      float s, c;
      fsincos(xw0 * scA, &s, &c); e0[0] = (short)f2bf(s); e0[1] = (short)f2bf(c);
      fsincos(yw0 * scA, &s, &c); e0[2] = (short)f2bf(s); e0[3] = (short)f2bf(c);
      fsincos(xw0 * scB, &s, &c); e0[4] = (short)f2bf(s); e0[5] = (short)f2bf(c);
      fsincos(yw0 * scB, &s, &c); e0[6] = (short)f2bf(s); e0[7] = (short)f2bf(c);
      fsincos(xw * scA, &s, &c);  e1[0] = (short)f2bf(s); e1[1] = (short)f2bf(c);
                                  e2[0] = (short)f2bf(s * s); e2[1] = (short)f2bf(c * c);
      fsincos(yw * scA, &s, &c);  e1[2] = (short)f2bf(s); e1[3] = (short)f2bf(c);
                                  e2[2] = (short)f2bf(s * s); e2[3] = (short)f2bf(c * c);
      fsincos(xw * scB, &s, &c);  e1[4] = (short)f2bf(s); e1[5] = (short)f2bf(c);
                                  e2[4] = (short)f2bf(s * s); e2[5] = (short)f2bf(c * c);
      fsincos(yw * scB, &s, &c);  e1[6] = (short)f2bf(s); e1[7] = (short)f2bf(c);
                                  e2[6] = (short)f2bf(s * s); e2[7] = (short)f2bf(c * c);
      int swz = (pl & 7) << 4;
      *(bf16x8*)((char*)&enc[0][pl][0] + ((16 * qq) ^ swz)) = e0;
      *(bf16x8*)((char*)&enc[1][pl][0] + ((16 * qq) ^ swz)) = e1;
      *(bf16x8*)((char*)&enc[2][pl][0] + ((16 * qq) ^ swz)) = e2;
      if (qq == 0) {
        float s0, c0, s1, c1;
        fsincos(xw0 * 0.0625f, &s0, &c0);
        fsincos(xw  * 0.0625f, &s1, &c1);
        bf16x4 h0, h1, h2;
        h0[0] = (short)f2bf(xx); h0[1] = (short)f2bf(yy);
        h0[2] = (short)f2bf(s0); h0[3] = (short)f2bf(c0);
        h1[0] = (short)f2bf(xx); h1[1] = (short)f2bf(yy);
        h1[2] = (short)f2bf(s1); h1[3] = (short)f2bf(c1);
        h2[0] = (short)f2bf(xx * xx); h2[1] = (short)f2bf(yy * yy);
        h2[2] = (short)f2bf(s1 * s1); h2[3] = (short)f2bf(c1 * c1);
        *(bf16x4*)((char*)&enc[0][pl][0] + (64 ^ swz)) = h0;
        *(bf16x4*)((char*)&enc[1][pl][0] + (64 ^ swz)) = h1;
        *(bf16x4*)((char*)&enc[2][pl][0] + (64 ^ swz)) = h2;
        xyl[pl] = make_float4(xx, yy, xx * xx, yy * yy);
      }
    }
    __syncthreads();  // sync1: enc/xyl ready; prev iter's rt1 store pass done with outt

    // ======== M phase: 2 row-tiles, each staged through LDS then row-stored ========
#pragma unroll
    for (int rt = 0; rt < 2; ++rt) {
      bf16x8 Af[3][3];
      int p = rt * 32 + ln;
      int swz2 = (p & 7) << 4;
#pragma unroll
      for (int m = 0; m < 3; ++m)
#pragma unroll
        for (int s = 0; s < 3; ++s)
          Af[m][s] = *(const bf16x8*)((const char*)&enc[m][p][0] +
                                      ((s * 32 + hi * 16) ^ swz2));

      if (rt == 1) __syncthreads();  // sync3: rt0 store pass done reading outt

#pragma unroll
      for (int ct = 0; ct < 2; ++ct) {
        f32x16 ar, ag, aq;
#pragma unroll
        for (int i = 0; i < 16; ++i) { ar[i] = 0.f; ag[i] = 0.f; aq[i] = 0.f; }
#pragma unroll
        for (int s = 0; s < 3; ++s) {
          ar = __builtin_amdgcn_mfma_f32_32x32x16_bf16(Af[0][s], Bf[ct][0][s], ar, 0, 0, 0);
          ag = __builtin_amdgcn_mfma_f32_32x32x16_bf16(Af[1][s], Bf[ct][1][s], ag, 0, 0, 0);
          aq = __builtin_amdgcn_mfma_f32_32x32x16_bf16(Af[2][s], Bf[ct][2][s], aq, 0, 0, 0);
        }
        int col = wid * 64 + ct * 32 + ln;
#pragma unroll
        for (int i = 0; i < 16; ++i) {
          int rl = (i & 3) + 8 * (i >> 2) + 4 * hi;   // row within 32-tile
          float4 xy = xyl[rt * 32 + rl];
          float rr = ar[i] + xy.x * wc[ct][0] + xy.y * wc[ct][1] + bs[ct][0];
          float gg = ag[i] + xy.x * wc[ct][2] + xy.y * wc[ct][3] + bs[ct][1];
          float qv = aq[i] + xy.z * wc[ct][4] + xy.w * wc[ct][5] + bs[ct][2];
          outt[rl][col] = rr * gg + qv;   // bank = col%32 = ln -> conflict-free
        }
      }
      __syncthreads();  // sync2/sync4: outt tile complete

      // store pass: one full 1KB output row per wave-instruction
      {
        const float* src = &outt[0][0];
        size_t base = (size_t)(t * 64 + rt * 32) * 256;
#pragma unroll
        for (int it = 0; it < 8; ++it) {
          int idx = it * 1024 + tid * 4;   // f32 index; wave covers one full row
          f32x4 v = *(const f32x4*)(src + idx);
          __builtin_nontemporal_store(v, (f32x4*)(Out + base + idx));
        }
      }
    }
    __syncthreads();  // protect enc/xyl before next E phase overwrite
  }
}

extern "C" void kernel_launch(void* const* d_in, const int* in_sizes, int n_in,
                              void* d_out, int out_size, void* d_ws, size_t ws_size,
                              hipStream_t stream) {
  const float* X  = (const float*)d_in[0];
  const float* Y  = (const float*)d_in[1];
  const float* V  = (const float*)d_in[2];
  const float* V0 = (const float*)d_in[3];
  const float* Wr = (const float*)d_in[4];
  const float* Wg = (const float*)d_in[5];
  const float* Wb = (const float*)d_in[6];
  const float* Br = (const float*)d_in[7];
  const float* Bg = (const float*)d_in[8];
  const float* Bb = (const float*)d_in[9];
  float* Out = (float*)d_out;
  int n  = in_sizes[0];
  int nt = n >> 6;  // N=1e6 is divisible by 64
  qpe_kernel<<<dim3(1024), dim3(256), 0, stream>>>(X, Y, V, V0, Wr, Wg, Wb,
                                                   Br, Bg, Bb, Out, nt);
}